// Round 10
// baseline (17925.145 us; speedup 1.0000x reference)
//
#include <hip/hip_runtime.h>

// Seq2Seq VAE fused persistent kernel for MI355X (gfx950).
// 16 groups of 16 WGs keyed by M-tile. TWO-STREAM software pipeline: each
// group's 64 batch rows split into A(0-31)/B(32-63); per-stream counters;
// the proven barrier split into release (vmcnt0+syncthreads+leader FAA) and
// acquire (leader poll+syncthreads) so stream X's barrier latency hides under
// stream Y's compute. Data exchange: XCD-detect -> sc0 (L2) else sc0sc1.
// Weights persistent in LDS; bf16 MFMA 16x16x32; 4-deep prefetch ladder.

#define NWG  256
#define NTHR 256

typedef __attribute__((ext_vector_type(8))) short short8;
typedef __attribute__((ext_vector_type(4))) float f32x4;
typedef __attribute__((ext_vector_type(4))) unsigned int u32x4;

constexpr int Bt = 1024, Tt = 1024, In = 64, Hn = 512, Ln = 64;
constexpr int KE = In + Hn;            // 576
constexpr int BSE = KE + 8;            // LDS row stride (shorts)
constexpr int KD = Hn;                 // 512
constexpr int BSD = KD + 8;
constexpr int HSTn = 40;               // h-stage row stride (shorts), 32 rows
constexpr int LDS_BYTES = 128 * BSE * 2 + 32 * HSTn * 2;  // 149504+2560=152064

template<bool B> struct BoolC { static constexpr bool value = B; };

__device__ __forceinline__ float bf2f(unsigned short s){
  unsigned u = ((unsigned)s) << 16; float f; __builtin_memcpy(&f, &u, 4); return f;
}
__device__ __forceinline__ unsigned short f2bf(float f){
  unsigned u; __builtin_memcpy(&u, &f, 4);
  u += 0x7FFFu + ((u >> 16) & 1u);
  return (unsigned short)(u >> 16);
}
__device__ __forceinline__ float sigm(float x){ return 1.0f / (1.0f + __expf(-x)); }
__device__ __forceinline__ float tanh_(float x){ float e = __expf(2.0f * x); return 1.0f - 2.0f / (e + 1.0f); }

// ---------------- raw VMEM helpers (SAME => XCD-local L2, else MALL) -------
template<bool SAME, int OFF>
__device__ __forceinline__ u32x4 ldA(const void* p){
  u32x4 r;
  if constexpr (SAME) asm volatile("global_load_dwordx4 %0, %1, off offset:%c2 sc0" : "=&v"(r) : "v"(p), "i"(OFF));
  else                asm volatile("global_load_dwordx4 %0, %1, off offset:%c2 sc0 sc1" : "=&v"(r) : "v"(p), "i"(OFF));
  return r;
}
template<int OFF>
__device__ __forceinline__ u32x4 ldP(const void* p){   // plain cached load
  u32x4 r;
  asm volatile("global_load_dwordx4 %0, %1, off offset:%c2" : "=&v"(r) : "v"(p), "i"(OFF));
  return r;
}
template<bool SAME>
__device__ __forceinline__ float ld32w(const void* p){ // load + drain (cold path)
  float r;
  if constexpr (SAME) asm volatile("global_load_dword %0, %1, off sc0" : "=&v"(r) : "v"(p));
  else                asm volatile("global_load_dword %0, %1, off sc0 sc1" : "=&v"(r) : "v"(p));
  asm volatile("s_waitcnt vmcnt(0)" : "+v"(r));
  return r;
}
template<bool SAME>
__device__ __forceinline__ void st16x(void* p, unsigned v){
  if constexpr (SAME) asm volatile("global_store_short %0, %1, off sc0" :: "v"(p), "v"(v) : "memory");
  else                asm volatile("global_store_short %0, %1, off sc0 sc1" :: "v"(p), "v"(v) : "memory");
}
template<bool SAME>
__device__ __forceinline__ void st32x(void* p, float v){
  if constexpr (SAME) asm volatile("global_store_dword %0, %1, off sc0" :: "v"(p), "v"(v) : "memory");
  else                asm volatile("global_store_dword %0, %1, off sc0 sc1" :: "v"(p), "v"(v) : "memory");
}
template<bool SAME>
__device__ __forceinline__ void st128x(void* p, u32x4 v){
  if constexpr (SAME) asm volatile("global_store_dwordx4 %0, %1, off sc0" :: "v"(p), "v"(v) : "memory");
  else                asm volatile("global_store_dwordx4 %0, %1, off sc0 sc1" :: "v"(p), "v"(v) : "memory");
}
__device__ __forceinline__ void stP32(void* p, float v){
  asm volatile("global_store_dword %0, %1, off" :: "v"(p), "v"(v) : "memory");
}
__device__ __forceinline__ void atomAddF(float* p, float v){
  asm volatile("global_atomic_add_f32 %0, %1, off" :: "v"(p), "v"(v) : "memory");
}
// MALL-scope raw dword pair (XCD-detect publication only; proven)
__device__ __forceinline__ unsigned ldMall(const unsigned* p){
  unsigned r;
  asm volatile("global_load_dword %0, %1, off sc0 sc1" : "=&v"(r) : "v"(p) : "memory");
  asm volatile("s_waitcnt vmcnt(0)" : "+v"(r) :: "memory");
  return r;
}
__device__ __forceinline__ void stMall(unsigned* p, unsigned v){
  asm volatile("global_store_dword %0, %1, off sc0 sc1" :: "v"(p), "v"(v) : "memory");
}

// PROVEN barrier split into halves (same primitives as R2/R5/R8/R9 barrier):
// release: drain all this-WG stores, join, leader FAA (fire-and-forget).
// acquire: leader polls counter to target, broadcast via syncthreads.
__device__ __forceinline__ void release(unsigned* cnt){
  asm volatile("s_waitcnt vmcnt(0)" ::: "memory");
  __syncthreads();
  if (threadIdx.x == 0)
    __hip_atomic_fetch_add(cnt, 1u, __ATOMIC_RELAXED, __HIP_MEMORY_SCOPE_AGENT);
}
__device__ __forceinline__ void acquire(unsigned* cnt, unsigned target){
  if (threadIdx.x == 0 && target){
    int g = 0;
    while (__hip_atomic_load(cnt, __ATOMIC_RELAXED, __HIP_MEMORY_SCOPE_AGENT) < target){
      if (++g > (1 << 20)) break;          // watchdog: wrong answer, never hang
      __builtin_amdgcn_s_sleep(1);
    }
  }
  __syncthreads();
}

#define LOADC1(C, CB) do{                                  \
    A[C][0] = ldA<SAME, ((CB) +  0) * 2>(ap);              \
    A[C][1] = ldA<SAME, ((CB) + 32) * 2>(ap);              \
    A[C][2] = ldA<SAME, ((CB) + 64) * 2>(ap);              \
    A[C][3] = ldA<SAME, ((CB) + 96) * 2>(ap); }while(0)

#define TIE1(C) "+v"(A[C][0]), "+v"(A[C][1]), "+v"(A[C][2]), "+v"(A[C][3])
#define WAITC1(C, N) asm volatile("s_waitcnt vmcnt(" N ")" : TIE1(C))

#define COMPC1(C, K0, BS) do{                                                    \
    _Pragma("unroll") for (int ti_ = 0; ti_ < 4; ++ti_){                         \
      short8 a_ = __builtin_bit_cast(short8, A[C][ti_]);                         \
      _Pragma("unroll") for (int ni_ = 0; ni_ < 4; ++ni_){                       \
        short8 bv_ = *(const short8*)(bbase + ni_ * 16 * (BS) + (K0) + ti_ * 32);\
        acc[ni_] = __builtin_amdgcn_mfma_f32_16x16x32_bf16(a_, bv_, acc[ni_], 0, 0, 0); \
      } } }while(0)

extern "C" __global__ void __launch_bounds__(NTHR, 1)
vae_fused(const float* __restrict__ src, const float* __restrict__ eps,
          const float* __restrict__ Wih_e, const float* __restrict__ Whh_e, const float* __restrict__ b_e,
          const float* __restrict__ Wmu, const float* __restrict__ bmu,
          const float* __restrict__ Wlv, const float* __restrict__ blv,
          const float* __restrict__ Wzh, const float* __restrict__ bzh,
          const float* __restrict__ Wzc, const float* __restrict__ bzc,
          const float* __restrict__ Wih_d, const float* __restrict__ Whh_d, const float* __restrict__ b_d,
          const float* __restrict__ Wout, const float* __restrict__ bout,
          float* __restrict__ out,
          unsigned* cntF_all, unsigned* cntA_all, unsigned* cntB_all, unsigned* xcdbuf,
          unsigned short* hbuf0, unsigned short* hbuf1,
          float* zbuf, float* obuf)
{
  const int tid  = threadIdx.x;
  const int wg   = blockIdx.x;
  const int lane = tid & 63;
  const int wave = tid >> 6;
  const int wm   = wave >> 1, wn = wave & 1;
  const int mt   = wg & 15;                 // group id
  const int nt   = wg >> 4;                 // N tile within group
  unsigned* cntF = cntF_all + mt * 16;      // 64B-spaced counters
  unsigned* cntA = cntA_all + mt * 16;
  unsigned* cntB = cntB_all + mt * 16;
  unsigned barsF = 0;

  extern __shared__ short bpanel[];
  unsigned short* hst = (unsigned short*)(bpanel + 128 * BSE);  // 32 x HSTn

  const int l15 = lane & 15;
  const int l4  = lane >> 4;
  const int kq  = l4 * 8;
  const int jcol = nt * 32 + wn * 16 + l15;

  // ---- XCD-affinity detect (proven: MALL publish + atomic barrier) ----
  unsigned xcc;
  asm volatile("s_getreg_b32 %0, hwreg(HW_REG_XCC_ID)" : "=s"(xcc));
  if (tid == 0) stMall(xcdbuf + mt * 16 + nt, xcc + 1u);
  release(cntF); barsF += 16; acquire(cntF, barsF);
  unsigned vx = xcc + 1u;
  if (lane < 16) vx = ldMall(xcdbuf + mt * 16 + lane);
  const bool same_xcd = (__ballot(vx == xcc + 1u) == ~0ull);

  auto body = [&](auto SC){
    constexpr bool SAME = decltype(SC)::value;

    // -------- prep: zero h0, build encoder B panel --------
    {
      const int idx = nt * NTHR + tid;      // 4096 == 64 rows * 64 col8s
      const u32x4 z = {0u, 0u, 0u, 0u};
      st128x<SAME>(hbuf0 + (size_t)(mt * 64 + (idx >> 6)) * Hn + (idx & 63) * 8, z);
    }
    for (int idx = tid; idx < 128 * KE; idx += NTHR){
      int q = idx / KE;
      int k = idx - q * KE;
      int gate = (q >> 4) & 3, jl = q & 15, wnn = (q >> 6) & 1;
      int j = nt * 32 + wnn * 16 + jl;
      int r = gate * Hn + j;
      float w = (k < In) ? Wih_e[r * In + k] : Whh_e[(size_t)r * Hn + (k - In)];
      bpanel[q * BSE + k] = (short)f2bf(w);
    }
    float biasr[4], wihr[4];
    #pragma unroll
    for (int ni = 0; ni < 4; ++ni) biasr[ni] = b_e[ni * Hn + jcol];
    release(cntF); barsF += 16; acquire(cntF, barsF);

    float cA[4] = {0.f,0.f,0.f,0.f}, cB[4] = {0.f,0.f,0.f,0.f};
    const f32x4 fz = {0.f, 0.f, 0.f, 0.f};
    unsigned needA = 0, needB = 0;

    // -------- encoder phase (stream X, step t) --------
    auto enc_phase = [&](int X, int t, unsigned* cntX, unsigned need, float (&cX)[4]){
      const int arow = mt * 64 + X * 32 + wm * 16 + l15;
      const unsigned short* hs = (t & 1) ? hbuf1 : hbuf0;
      unsigned short*       hd = (t & 1) ? hbuf0 : hbuf1;

      // src loads before acquire (independent; latency hides under poll)
      const float* sp = src + ((size_t)arow * Tt + t) * In + kq;
      u32x4 sv0 = ldP<0>(sp), sv1 = ldP<16>(sp), sv2 = ldP<128>(sp), sv3 = ldP<144>(sp);

      acquire(cntX, need);

      const unsigned short* ap = hs + (size_t)arow * Hn + kq;
      u32x4 A[4][4];
      LOADC1(0,   0); LOADC1(1, 128); LOADC1(2, 256); LOADC1(3, 384);

      asm volatile("s_waitcnt vmcnt(16)" : "+v"(sv0), "+v"(sv1), "+v"(sv2), "+v"(sv3));
      f32x4 f0 = __builtin_bit_cast(f32x4, sv0);
      f32x4 f1 = __builtin_bit_cast(f32x4, sv1);
      f32x4 f2 = __builtin_bit_cast(f32x4, sv2);
      f32x4 f3 = __builtin_bit_cast(f32x4, sv3);
      short8 sa0, sa1;
      #pragma unroll
      for (int e = 0; e < 4; ++e){
        sa0[e] = (short)f2bf(f0[e]); sa0[4 + e] = (short)f2bf(f1[e]);
        sa1[e] = (short)f2bf(f2[e]); sa1[4 + e] = (short)f2bf(f3[e]);
      }

      f32x4 acc[4] = {fz, fz, fz, fz};
      const short* bbase = bpanel + (wn * 64 + l15) * BSE + kq;
      #pragma unroll
      for (int ni = 0; ni < 4; ++ni){
        short8 bv0 = *(const short8*)(bbase + ni * 16 * BSE + 0);
        short8 bv1 = *(const short8*)(bbase + ni * 16 * BSE + 32);
        acc[ni] = __builtin_amdgcn_mfma_f32_16x16x32_bf16(sa0, bv0, acc[ni], 0, 0, 0);
        acc[ni] = __builtin_amdgcn_mfma_f32_16x16x32_bf16(sa1, bv1, acc[ni], 0, 0, 0);
      }

      WAITC1(0, "12"); COMPC1(0, In +   0, BSE);
      WAITC1(1,  "8"); COMPC1(1, In + 128, BSE);
      WAITC1(2,  "4"); COMPC1(2, In + 256, BSE);
      WAITC1(3,  "0"); COMPC1(3, In + 384, BSE);

      #pragma unroll
      for (int r = 0; r < 4; ++r){
        float gi = acc[0][r] + biasr[0];
        float gf = acc[1][r] + biasr[1];
        float gg = acc[2][r] + biasr[2];
        float go = acc[3][r] + biasr[3];
        float cn = sigm(gf) * cX[r] + sigm(gi) * tanh_(gg);
        cX[r] = cn;
        float hn = sigm(go) * tanh_(cn);
        hst[(wm * 16 + l4 * 4 + r) * HSTn + wn * 16 + l15] = f2bf(hn);
      }
      __syncthreads();
      if (tid < 128){
        u32x4 hv = *(const u32x4*)(hst + (tid >> 2) * HSTn + (tid & 3) * 8);
        st128x<SAME>(hd + (size_t)(mt * 64 + X * 32 + (tid >> 2)) * Hn + nt * 32 + (tid & 3) * 8, hv);
      }
      release(cntX);
    };

    for (int t = 0; t < Tt; ++t){
      enc_phase(0, t, cntA, needA, cA); needA += 16;
      enc_phase(1, t, cntB, needB, cB); needB += 16;
    }
    release(cntF); barsF += 16; acquire(cntF, barsF);
    // h_n in hbuf0

    // -------- mu / logvar / z --------
    {
      const int lt = nt * NTHR + tid;
      const int b  = mt * 64 + (lt >> 6);
      const int l  = lt & 63;
      const unsigned short* hp = hbuf0 + (size_t)b * Hn;
      const float* wmrow = Wmu + l * Hn;
      const float* wlrow = Wlv + l * Hn;
      float smu = 0.f, slv = 0.f;
      for (int jj = 0; jj < Hn; jj += 32){
        u32x4 v0 = ldA<SAME,0>(hp + jj),  v1 = ldA<SAME,16>(hp + jj);
        u32x4 v2 = ldA<SAME,32>(hp + jj), v3 = ldA<SAME,48>(hp + jj);
        asm volatile("s_waitcnt vmcnt(0)" : "+v"(v0), "+v"(v1), "+v"(v2), "+v"(v3));
        short8 h0 = __builtin_bit_cast(short8, v0);
        short8 h1 = __builtin_bit_cast(short8, v1);
        short8 h2 = __builtin_bit_cast(short8, v2);
        short8 h3 = __builtin_bit_cast(short8, v3);
        #pragma unroll
        for (int e = 0; e < 8; ++e){
          float g0 = bf2f((unsigned short)h0[e]), g1 = bf2f((unsigned short)h1[e]);
          float g2 = bf2f((unsigned short)h2[e]), g3 = bf2f((unsigned short)h3[e]);
          smu = __builtin_fmaf(g0, wmrow[jj + e], smu);      slv = __builtin_fmaf(g0, wlrow[jj + e], slv);
          smu = __builtin_fmaf(g1, wmrow[jj + 8 + e], smu);  slv = __builtin_fmaf(g1, wlrow[jj + 8 + e], slv);
          smu = __builtin_fmaf(g2, wmrow[jj + 16 + e], smu); slv = __builtin_fmaf(g2, wlrow[jj + 16 + e], slv);
          smu = __builtin_fmaf(g3, wmrow[jj + 24 + e], smu); slv = __builtin_fmaf(g3, wlrow[jj + 24 + e], slv);
        }
      }
      smu += bmu[l]; slv += blv[l];
      out[(size_t)Bt * Tt + (size_t)b * Ln + l] = smu;
      out[(size_t)Bt * Tt + (size_t)Bt * Ln + (size_t)b * Ln + l] = slv;
      st32x<SAME>(zbuf + (size_t)b * Ln + l, smu + eps[(size_t)b * Ln + l] * __expf(0.5f * slv));
    }
    release(cntF); barsF += 16; acquire(cntF, barsF);

    // -------- decoder init --------
    for (int idx = tid; idx < 128 * KD; idx += NTHR){
      int q = idx >> 9, k = idx & 511;
      int gate = (q >> 4) & 3, jl = q & 15, wnn = (q >> 6) & 1;
      int j = nt * 32 + wnn * 16 + jl;
      bpanel[q * BSD + k] = (short)f2bf(Whh_d[(size_t)(gate * Hn + j) * Hn + k]);
    }
    #pragma unroll
    for (int ni = 0; ni < 4; ++ni){
      biasr[ni] = b_d[ni * Hn + jcol];
      wihr[ni]  = Wih_d[ni * Hn + jcol];
    }
    const float woutr = Wout[jcol];
    const float bov   = bout[0];

    auto dec_init = [&](int X, float (&cX)[4]){
      #pragma unroll
      for (int r = 0; r < 4; ++r){
        int b = mt * 64 + X * 32 + wm * 16 + l4 * 4 + r;
        const float* zp  = zbuf + (size_t)b * Ln;
        const float* whr = Wzh + jcol * Ln;
        const float* wcr = Wzc + jcol * Ln;
        float sh = bzh[jcol], sc = bzc[jcol];
        for (int e0 = 0; e0 < Ln; e0 += 16){
          u32x4 z0 = ldA<SAME,0>(zp + e0),  z1 = ldA<SAME,16>(zp + e0);
          u32x4 z2 = ldA<SAME,32>(zp + e0), z3 = ldA<SAME,48>(zp + e0);
          asm volatile("s_waitcnt vmcnt(0)" : "+v"(z0), "+v"(z1), "+v"(z2), "+v"(z3));
          f32x4 zf0 = __builtin_bit_cast(f32x4, z0);
          f32x4 zf1 = __builtin_bit_cast(f32x4, z1);
          f32x4 zf2 = __builtin_bit_cast(f32x4, z2);
          f32x4 zf3 = __builtin_bit_cast(f32x4, z3);
          #pragma unroll
          for (int e = 0; e < 4; ++e){
            sh = __builtin_fmaf(zf0[e], whr[e0 + e], sh);      sc = __builtin_fmaf(zf0[e], wcr[e0 + e], sc);
            sh = __builtin_fmaf(zf1[e], whr[e0 + 4 + e], sh);  sc = __builtin_fmaf(zf1[e], wcr[e0 + 4 + e], sc);
            sh = __builtin_fmaf(zf2[e], whr[e0 + 8 + e], sh);  sc = __builtin_fmaf(zf2[e], wcr[e0 + 8 + e], sc);
            sh = __builtin_fmaf(zf3[e], whr[e0 + 12 + e], sh); sc = __builtin_fmaf(zf3[e], wcr[e0 + 12 + e], sc);
          }
        }
        cX[r] = tanh_(sc);
        st16x<SAME>(hbuf0 + (size_t)b * Hn + jcol, (unsigned)f2bf(tanh_(sh)));
      }
    };
    dec_init(0, cA);
    dec_init(1, cB);
    if (nt == 0 && tid < 3 * 64)
      st32x<SAME>(obuf + (tid >> 6) * Bt + mt * 64 + (tid & 63), bov);
    release(cntF); barsF += 16; acquire(cntF, barsF);

    // -------- decoder phase (stream X, step t) --------
    auto dec_phase = [&](int X, int t, unsigned* cntX, unsigned need, float (&cX)[4]){
      const int arow = mt * 64 + X * 32 + wm * 16 + l15;
      const int brow = mt * 64 + X * 32 + wm * 16 + l4 * 4;
      const int rX0  = mt * 64 + X * 32;
      const unsigned short* hs = (t & 1) ? hbuf1 : hbuf0;
      unsigned short*       hd = (t & 1) ? hbuf0 : hbuf1;
      float*       oacc  = obuf + (t % 3) * Bt;
      const float* oread = obuf + ((t + 2) % 3) * Bt;
      float*       orst  = obuf + ((t + 1) % 3) * Bt;

      acquire(cntX, need);

      if (nt == 0){
        if (t > 0 && tid < 32){
          float w = ld32w<SAME>(oread + rX0 + tid);
          stP32(out + (size_t)(rX0 + tid) * Tt + (t - 1), w);
        }
        if (tid < 32) st32x<SAME>(orst + rX0 + tid, bov);
      }

      u32x4 xvv = ldA<SAME, 0>(oread + brow);
      const unsigned short* ap = hs + (size_t)arow * Hn + kq;
      u32x4 A[4][4];
      LOADC1(0,   0); LOADC1(1, 128); LOADC1(2, 256); LOADC1(3, 384);

      f32x4 acc[4] = {fz, fz, fz, fz};
      const short* bbase = bpanel + (wn * 64 + l15) * BSD + kq;
      WAITC1(0, "12"); COMPC1(0,   0, BSD);
      WAITC1(1,  "8"); COMPC1(1, 128, BSD);
      WAITC1(2,  "4"); COMPC1(2, 256, BSD);
      WAITC1(3,  "0"); COMPC1(3, 384, BSD);
      asm volatile("s_waitcnt vmcnt(0)" : "+v"(xvv));
      f32x4 xf = __builtin_bit_cast(f32x4, xvv);

      #pragma unroll
      for (int r = 0; r < 4; ++r){
        float x = (t == 0) ? 0.f : xf[r];
        float gi = acc[0][r] + biasr[0] + x * wihr[0];
        float gf = acc[1][r] + biasr[1] + x * wihr[1];
        float gg = acc[2][r] + biasr[2] + x * wihr[2];
        float go = acc[3][r] + biasr[3] + x * wihr[3];
        float cn = sigm(gf) * cX[r] + sigm(gi) * tanh_(gg);
        cX[r] = cn;
        float hn = sigm(go) * tanh_(cn);
        hst[(wm * 16 + l4 * 4 + r) * HSTn + wn * 16 + l15] = f2bf(hn);
        float pv = hn * woutr;
        pv += __shfl_xor(pv, 1);
        pv += __shfl_xor(pv, 2);
        pv += __shfl_xor(pv, 4);
        pv += __shfl_xor(pv, 8);
        if (l15 == 0) atomAddF(&oacc[brow + r], pv);
      }
      __syncthreads();
      if (tid < 128){
        u32x4 hv = *(const u32x4*)(hst + (tid >> 2) * HSTn + (tid & 3) * 8);
        st128x<SAME>(hd + (size_t)(mt * 64 + X * 32 + (tid >> 2)) * Hn + nt * 32 + (tid & 3) * 8, hv);
      }
      release(cntX);
    };

    for (int t = 0; t < Tt; ++t){
      dec_phase(0, t, cntA, needA, cA); needA += 16;
      dec_phase(1, t, cntB, needB, cB); needB += 16;
    }
    release(cntF); barsF += 16; acquire(cntF, barsF);

    // drain last output column (t=1023 accumulated into buf (1023%3)==0)
    if (nt == 0 && tid < 64){
      float w = ld32w<SAME>(obuf + 0 * Bt + mt * 64 + tid);
      stP32(out + (size_t)(mt * 64 + tid) * Tt + (Tt - 1), w);
    }
  };

  if (same_xcd) body(BoolC<true>{});
  else          body(BoolC<false>{});
}

extern "C" void kernel_launch(void* const* d_in, const int* in_sizes, int n_in,
                              void* d_out, int out_size, void* d_ws, size_t ws_size,
                              hipStream_t stream){
  (void)in_sizes; (void)n_in; (void)out_size; (void)ws_size;
  const float* src   = (const float*)d_in[0];
  const float* eps   = (const float*)d_in[1];
  const float* Wih_e = (const float*)d_in[3];
  const float* Whh_e = (const float*)d_in[4];
  const float* b_e   = (const float*)d_in[5];
  const float* Wmu   = (const float*)d_in[6];
  const float* bmu   = (const float*)d_in[7];
  const float* Wlv   = (const float*)d_in[8];
  const float* blv   = (const float*)d_in[9];
  const float* Wzh   = (const float*)d_in[10];
  const float* bzh   = (const float*)d_in[11];
  const float* Wzc   = (const float*)d_in[12];
  const float* bzc   = (const float*)d_in[13];
  const float* Wih_d = (const float*)d_in[14];
  const float* Whh_d = (const float*)d_in[15];
  const float* b_d   = (const float*)d_in[16];
  const float* Wout  = (const float*)d_in[17];
  const float* bout  = (const float*)d_in[18];

  char* ws = (char*)d_ws;
  unsigned*       cntF  = (unsigned*)ws;                             // 16 x 64B
  unsigned*       cntA  = (unsigned*)(ws + 1024);                    // 16 x 64B
  unsigned*       cntB  = (unsigned*)(ws + 2048);                    // 16 x 64B
  unsigned*       xcdb  = (unsigned*)(ws + 3072);                    // 16 x 64B
  unsigned short* h0    = (unsigned short*)(ws + 4096);              // 1 MB
  unsigned short* h1    = (unsigned short*)(ws + 4096 + 1048576);    // 1 MB
  float*          zbuf  = (float*)(ws + 4096 + 2 * 1048576);         // 256 KB
  float*          obuf  = (float*)(ws + 4096 + 2 * 1048576 + 262144);// 12 KB

  hipFuncSetAttribute((const void*)vae_fused,
                      hipFuncAttributeMaxDynamicSharedMemorySize, LDS_BYTES);
  (void)hipMemsetAsync(ws, 0, 4096, stream);
  hipLaunchKernelGGL(vae_fused, dim3(NWG), dim3(NTHR), LDS_BYTES, stream,
                     src, eps, Wih_e, Whh_e, b_e, Wmu, bmu, Wlv, blv,
                     Wzh, bzh, Wzc, bzc, Wih_d, Whh_d, b_d, Wout, bout,
                     (float*)d_out, cntF, cntA, cntB, xcdb, h0, h1, zbuf, obuf);
}

// Round 11
// 14996.442 us; speedup vs baseline: 1.1953x; 1.1953x over previous
//
#include <hip/hip_runtime.h>

// Seq2Seq VAE fused persistent kernel for MI355X (gfx950).
// R11 = R9 with 512-thread WGs (8 waves -> 2 waves/SIMD) to hide per-wave
// latency (MFMA issue-block, ds_read, VMEM). Wave tile 4m x 2j: 16 rows x
// (4 gates x 16 j) per wave, acc[4]. Groups (16 x 16 WGs), agent-atomic FAA
// barrier, XCD-detect sc0/sc0sc1 data paths, LDS-staged st128 h publish,
// 4-deep prefetch ladder: all unchanged from R9 (proven).

#define NWG  256
#define NTHR 512

typedef __attribute__((ext_vector_type(8))) short short8;
typedef __attribute__((ext_vector_type(4))) float f32x4;
typedef __attribute__((ext_vector_type(4))) unsigned int u32x4;

constexpr int Bt = 1024, Tt = 1024, In = 64, Hn = 512, Ln = 64;
constexpr int KE = In + Hn;            // 576
constexpr int BSE = KE + 8;            // LDS row stride (shorts)
constexpr int KD = Hn;                 // 512
constexpr int BSD = KD + 8;
constexpr int HST = 40;                // h-stage row stride (shorts), 32 cols
constexpr int LDS_BYTES = 128 * BSE * 2 + 64 * HST * 2;  // 149504+5120=154624

template<bool B> struct BoolC { static constexpr bool value = B; };

__device__ __forceinline__ float bf2f(unsigned short s){
  unsigned u = ((unsigned)s) << 16; float f; __builtin_memcpy(&f, &u, 4); return f;
}
__device__ __forceinline__ unsigned short f2bf(float f){
  unsigned u; __builtin_memcpy(&u, &f, 4);
  u += 0x7FFFu + ((u >> 16) & 1u);
  return (unsigned short)(u >> 16);
}
__device__ __forceinline__ float sigm(float x){ return 1.0f / (1.0f + __expf(-x)); }
__device__ __forceinline__ float tanh_(float x){ float e = __expf(2.0f * x); return 1.0f - 2.0f / (e + 1.0f); }

// ---------------- raw VMEM helpers (SAME => XCD-local L2, else MALL) -------
template<bool SAME, int OFF>
__device__ __forceinline__ u32x4 ldA(const void* p){
  u32x4 r;
  if constexpr (SAME) asm volatile("global_load_dwordx4 %0, %1, off offset:%c2 sc0" : "=&v"(r) : "v"(p), "i"(OFF));
  else                asm volatile("global_load_dwordx4 %0, %1, off offset:%c2 sc0 sc1" : "=&v"(r) : "v"(p), "i"(OFF));
  return r;
}
template<int OFF>
__device__ __forceinline__ u32x4 ldP(const void* p){   // plain cached load
  u32x4 r;
  asm volatile("global_load_dwordx4 %0, %1, off offset:%c2" : "=&v"(r) : "v"(p), "i"(OFF));
  return r;
}
template<bool SAME>
__device__ __forceinline__ float ld32w(const void* p){ // load + drain (cold path)
  float r;
  if constexpr (SAME) asm volatile("global_load_dword %0, %1, off sc0" : "=&v"(r) : "v"(p));
  else                asm volatile("global_load_dword %0, %1, off sc0 sc1" : "=&v"(r) : "v"(p));
  asm volatile("s_waitcnt vmcnt(0)" : "+v"(r));
  return r;
}
template<bool SAME>
__device__ __forceinline__ void st16x(void* p, unsigned v){
  if constexpr (SAME) asm volatile("global_store_short %0, %1, off sc0" :: "v"(p), "v"(v) : "memory");
  else                asm volatile("global_store_short %0, %1, off sc0 sc1" :: "v"(p), "v"(v) : "memory");
}
template<bool SAME>
__device__ __forceinline__ void st32x(void* p, float v){
  if constexpr (SAME) asm volatile("global_store_dword %0, %1, off sc0" :: "v"(p), "v"(v) : "memory");
  else                asm volatile("global_store_dword %0, %1, off sc0 sc1" :: "v"(p), "v"(v) : "memory");
}
template<bool SAME>
__device__ __forceinline__ void st128x(void* p, u32x4 v){
  if constexpr (SAME) asm volatile("global_store_dwordx4 %0, %1, off sc0" :: "v"(p), "v"(v) : "memory");
  else                asm volatile("global_store_dwordx4 %0, %1, off sc0 sc1" :: "v"(p), "v"(v) : "memory");
}
__device__ __forceinline__ void stP32(void* p, float v){
  asm volatile("global_store_dword %0, %1, off" :: "v"(p), "v"(v) : "memory");
}
template<bool SAME>
__device__ __forceinline__ void atomAddF(float* p, float v){
  if constexpr (SAME) asm volatile("global_atomic_add_f32 %0, %1, off" :: "v"(p), "v"(v) : "memory");
  else                asm volatile("global_atomic_add_f32 %0, %1, off sc1" :: "v"(p), "v"(v) : "memory");
}
// MALL-scope raw dword pair (XCD-detect publication only; proven)
__device__ __forceinline__ unsigned ldMall(const unsigned* p){
  unsigned r;
  asm volatile("global_load_dword %0, %1, off sc0 sc1" : "=&v"(r) : "v"(p) : "memory");
  asm volatile("s_waitcnt vmcnt(0)" : "+v"(r) :: "memory");
  return r;
}
__device__ __forceinline__ void stMall(unsigned* p, unsigned v){
  asm volatile("global_store_dword %0, %1, off sc0 sc1" :: "v"(p), "v"(v) : "memory");
}

// PROVEN group barrier (replay-safe): drain this wave's stores, join WG,
// leader FAA + poll at agent scope (coherence point).
__device__ __forceinline__ void group_sync(unsigned* cnt, unsigned target){
  asm volatile("s_waitcnt vmcnt(0)" ::: "memory");
  __syncthreads();
  if (threadIdx.x == 0){
    __hip_atomic_fetch_add(cnt, 1u, __ATOMIC_RELAXED, __HIP_MEMORY_SCOPE_AGENT);
    while (__hip_atomic_load(cnt, __ATOMIC_RELAXED, __HIP_MEMORY_SCOPE_AGENT) < target)
      __builtin_amdgcn_s_sleep(1);
  }
  __syncthreads();
}

#define LOADC1(C, CB) do{                                  \
    A[C][0] = ldA<SAME, ((CB) +  0) * 2>(ap);              \
    A[C][1] = ldA<SAME, ((CB) + 32) * 2>(ap);              \
    A[C][2] = ldA<SAME, ((CB) + 64) * 2>(ap);              \
    A[C][3] = ldA<SAME, ((CB) + 96) * 2>(ap); }while(0)

#define TIE1(C) "+v"(A[C][0]), "+v"(A[C][1]), "+v"(A[C][2]), "+v"(A[C][3])
#define WAITC1(C, N) asm volatile("s_waitcnt vmcnt(" N ")" : TIE1(C))

#define COMPC1(C, K0, BS) do{                                                    \
    _Pragma("unroll") for (int ti_ = 0; ti_ < 4; ++ti_){                         \
      short8 a_ = __builtin_bit_cast(short8, A[C][ti_]);                         \
      _Pragma("unroll") for (int ni_ = 0; ni_ < 4; ++ni_){                       \
        short8 bv_ = *(const short8*)(bbase + ni_ * 16 * (BS) + (K0) + ti_ * 32);\
        acc[ni_] = __builtin_amdgcn_mfma_f32_16x16x32_bf16(a_, bv_, acc[ni_], 0, 0, 0); \
      } } }while(0)

extern "C" __global__ void __launch_bounds__(NTHR, 2)
vae_fused(const float* __restrict__ src, const float* __restrict__ eps,
          const float* __restrict__ Wih_e, const float* __restrict__ Whh_e, const float* __restrict__ b_e,
          const float* __restrict__ Wmu, const float* __restrict__ bmu,
          const float* __restrict__ Wlv, const float* __restrict__ blv,
          const float* __restrict__ Wzh, const float* __restrict__ bzh,
          const float* __restrict__ Wzc, const float* __restrict__ bzc,
          const float* __restrict__ Wih_d, const float* __restrict__ Whh_d, const float* __restrict__ b_d,
          const float* __restrict__ Wout, const float* __restrict__ bout,
          float* __restrict__ out,
          unsigned* cnt_all, unsigned* xcdbuf,
          unsigned short* hbuf0, unsigned short* hbuf1,
          float* zbuf, float* obuf)
{
  const int tid  = threadIdx.x;
  const int wg   = blockIdx.x;
  const int lane = tid & 63;
  const int wave = tid >> 6;                // 0..7
  const int wm   = wave >> 1;               // 0..3 : 16-row block
  const int wn   = wave & 1;                // 0..1 : 16-j half
  const int mt   = wg & 15;                 // group id
  const int nt   = wg >> 4;                 // N tile within group
  unsigned* cnt  = cnt_all + mt * 32;       // 128B-spaced counters
  unsigned bars  = 0;

  extern __shared__ short bpanel[];
  unsigned short* hst = (unsigned short*)(bpanel + 128 * BSE);  // 64 x HST

  const int l15   = lane & 15;
  const int l4    = lane >> 4;
  const int kq    = l4 * 8;
  const int jcol  = nt * 32 + wn * 16 + l15;
  const int arow0 = mt * 64 + wm * 16 + l15;
  const int brow0 = mt * 64 + wm * 16 + l4 * 4;

  // ---- XCD-affinity detect (proven: MALL publish + atomic barrier) ----
  unsigned xcc;
  asm volatile("s_getreg_b32 %0, hwreg(HW_REG_XCC_ID)" : "=s"(xcc));
  if (tid == 0) stMall(xcdbuf + mt * 16 + nt, xcc + 1u);
  bars += 16; group_sync(cnt, bars);
  unsigned vx = xcc + 1u;
  if (lane < 16) vx = ldMall(xcdbuf + mt * 16 + lane);
  const bool same_xcd = (__ballot(vx == xcc + 1u) == ~0ull);

  auto body = [&](auto SC){
    constexpr bool SAME = decltype(SC)::value;

    // -------- prep: zero h0 (disjoint slices), build encoder B panel --------
    {
      const int idx = nt * NTHR + tid;      // 0..8191; need 4096 st128
      if (idx < 4096){
        const u32x4 z = {0u, 0u, 0u, 0u};
        st128x<SAME>(hbuf0 + (size_t)(mt * 64 + (idx >> 6)) * Hn + (idx & 63) * 8, z);
      }
    }
    for (int idx = tid; idx < 128 * KE; idx += NTHR){
      int q = idx / KE;
      int k = idx - q * KE;
      int gate = (q >> 4) & 3, jl = q & 15, wnn = (q >> 6) & 1;
      int j = nt * 32 + wnn * 16 + jl;
      int r = gate * Hn + j;
      float w = (k < In) ? Wih_e[r * In + k] : Whh_e[(size_t)r * Hn + (k - In)];
      bpanel[q * BSE + k] = (short)f2bf(w);
    }
    float biasr[4], wihr[4];
    #pragma unroll
    for (int ni = 0; ni < 4; ++ni) biasr[ni] = b_e[ni * Hn + jcol];
    bars += 16; group_sync(cnt, bars);

    float c[4] = {0.f, 0.f, 0.f, 0.f};
    const f32x4 fz = {0.f, 0.f, 0.f, 0.f};
    u32x4 A[4][4];

    // -------- encoder: 1024 steps --------
    for (int t = 0; t < Tt; ++t){
      const unsigned short* hs = (t & 1) ? hbuf1 : hbuf0;
      unsigned short*       hd = (t & 1) ? hbuf0 : hbuf1;

      // src loads first (read-only input, plain cached)
      const float* sp = src + ((size_t)arow0 * Tt + t) * In + kq;
      u32x4 sv0 = ldP<0>(sp), sv1 = ldP<16>(sp), sv2 = ldP<128>(sp), sv3 = ldP<144>(sp);

      // issue ALL h chunks (16 insts) — 4-deep prefetch
      const unsigned short* ap = hs + (size_t)arow0 * Hn + kq;
      LOADC1(0,   0); LOADC1(1, 128); LOADC1(2, 256); LOADC1(3, 384);

      asm volatile("s_waitcnt vmcnt(16)" : "+v"(sv0), "+v"(sv1), "+v"(sv2), "+v"(sv3));
      f32x4 f0 = __builtin_bit_cast(f32x4, sv0);
      f32x4 f1 = __builtin_bit_cast(f32x4, sv1);
      f32x4 f2 = __builtin_bit_cast(f32x4, sv2);
      f32x4 f3 = __builtin_bit_cast(f32x4, sv3);
      short8 sa0, sa1;
      #pragma unroll
      for (int e = 0; e < 4; ++e){
        sa0[e] = (short)f2bf(f0[e]); sa0[4 + e] = (short)f2bf(f1[e]);
        sa1[e] = (short)f2bf(f2[e]); sa1[4 + e] = (short)f2bf(f3[e]);
      }

      f32x4 acc[4] = {fz, fz, fz, fz};
      const short* bbase = bpanel + (wn * 64 + l15) * BSE + kq;
      #pragma unroll
      for (int ni = 0; ni < 4; ++ni){
        short8 bv0 = *(const short8*)(bbase + ni * 16 * BSE + 0);
        short8 bv1 = *(const short8*)(bbase + ni * 16 * BSE + 32);
        acc[ni] = __builtin_amdgcn_mfma_f32_16x16x32_bf16(sa0, bv0, acc[ni], 0, 0, 0);
        acc[ni] = __builtin_amdgcn_mfma_f32_16x16x32_bf16(sa1, bv1, acc[ni], 0, 0, 0);
      }

      WAITC1(0, "12"); COMPC1(0, In +   0, BSE);
      WAITC1(1,  "8"); COMPC1(1, In + 128, BSE);
      WAITC1(2,  "4"); COMPC1(2, In + 256, BSE);
      WAITC1(3,  "0"); COMPC1(3, In + 384, BSE);

      // gates -> h; stage to LDS, publish as st128 lines, barrier
      #pragma unroll
      for (int r = 0; r < 4; ++r){
        float gi = acc[0][r] + biasr[0];
        float gf = acc[1][r] + biasr[1];
        float gg = acc[2][r] + biasr[2];
        float go = acc[3][r] + biasr[3];
        float cn = sigm(gf) * c[r] + sigm(gi) * tanh_(gg);
        c[r] = cn;
        float hn = sigm(go) * tanh_(cn);
        hst[(wm * 16 + l4 * 4 + r) * HST + wn * 16 + l15] = f2bf(hn);
      }
      __syncthreads();
      if (tid < 256){
        int row = tid >> 2, sub = tid & 3;
        u32x4 hv = *(const u32x4*)(hst + row * HST + sub * 8);
        st128x<SAME>(hd + (size_t)(mt * 64 + row) * Hn + nt * 32 + sub * 8, hv);
      }
      bars += 16; group_sync(cnt, bars);
    }
    // h_n in hbuf0

    // -------- mu / logvar / z --------
    {
      const int lt = nt * NTHR + tid;       // 0..8191; 4096 items
      if (lt < 4096){
        const int b  = mt * 64 + (lt >> 6);
        const int l  = lt & 63;
        const unsigned short* hp = hbuf0 + (size_t)b * Hn;
        const float* wmrow = Wmu + l * Hn;
        const float* wlrow = Wlv + l * Hn;
        float smu = 0.f, slv = 0.f;
        for (int jj = 0; jj < Hn; jj += 32){
          u32x4 v0 = ldA<SAME,0>(hp + jj),  v1 = ldA<SAME,16>(hp + jj);
          u32x4 v2 = ldA<SAME,32>(hp + jj), v3 = ldA<SAME,48>(hp + jj);
          asm volatile("s_waitcnt vmcnt(0)" : "+v"(v0), "+v"(v1), "+v"(v2), "+v"(v3));
          short8 h0 = __builtin_bit_cast(short8, v0);
          short8 h1 = __builtin_bit_cast(short8, v1);
          short8 h2 = __builtin_bit_cast(short8, v2);
          short8 h3 = __builtin_bit_cast(short8, v3);
          #pragma unroll
          for (int e = 0; e < 8; ++e){
            float g0 = bf2f((unsigned short)h0[e]), g1 = bf2f((unsigned short)h1[e]);
            float g2 = bf2f((unsigned short)h2[e]), g3 = bf2f((unsigned short)h3[e]);
            smu = __builtin_fmaf(g0, wmrow[jj + e], smu);      slv = __builtin_fmaf(g0, wlrow[jj + e], slv);
            smu = __builtin_fmaf(g1, wmrow[jj + 8 + e], smu);  slv = __builtin_fmaf(g1, wlrow[jj + 8 + e], slv);
            smu = __builtin_fmaf(g2, wmrow[jj + 16 + e], smu); slv = __builtin_fmaf(g2, wlrow[jj + 16 + e], slv);
            smu = __builtin_fmaf(g3, wmrow[jj + 24 + e], smu); slv = __builtin_fmaf(g3, wlrow[jj + 24 + e], slv);
          }
        }
        smu += bmu[l]; slv += blv[l];
        out[(size_t)Bt * Tt + (size_t)b * Ln + l] = smu;
        out[(size_t)Bt * Tt + (size_t)Bt * Ln + (size_t)b * Ln + l] = slv;
        st32x<SAME>(zbuf + (size_t)b * Ln + l, smu + eps[(size_t)b * Ln + l] * __expf(0.5f * slv));
      }
    }
    bars += 16; group_sync(cnt, bars);

    // -------- decoder init --------
    for (int idx = tid; idx < 128 * KD; idx += NTHR){
      int q = idx >> 9, k = idx & 511;
      int gate = (q >> 4) & 3, jl = q & 15, wnn = (q >> 6) & 1;
      int j = nt * 32 + wnn * 16 + jl;
      bpanel[q * BSD + k] = (short)f2bf(Whh_d[(size_t)(gate * Hn + j) * Hn + k]);
    }
    #pragma unroll
    for (int ni = 0; ni < 4; ++ni){
      biasr[ni] = b_d[ni * Hn + jcol];
      wihr[ni]  = Wih_d[ni * Hn + jcol];
    }
    const float woutr = Wout[jcol];
    const float bov   = bout[0];
    #pragma unroll
    for (int r = 0; r < 4; ++r){
      int b = brow0 + r;
      const float* zp  = zbuf + (size_t)b * Ln;
      const float* whr = Wzh + jcol * Ln;
      const float* wcr = Wzc + jcol * Ln;
      float sh = bzh[jcol], sc = bzc[jcol];
      for (int e0 = 0; e0 < Ln; e0 += 16){
        u32x4 z0 = ldA<SAME,0>(zp + e0),  z1 = ldA<SAME,16>(zp + e0);
        u32x4 z2 = ldA<SAME,32>(zp + e0), z3 = ldA<SAME,48>(zp + e0);
        asm volatile("s_waitcnt vmcnt(0)" : "+v"(z0), "+v"(z1), "+v"(z2), "+v"(z3));
        f32x4 zf0 = __builtin_bit_cast(f32x4, z0);
        f32x4 zf1 = __builtin_bit_cast(f32x4, z1);
        f32x4 zf2 = __builtin_bit_cast(f32x4, z2);
        f32x4 zf3 = __builtin_bit_cast(f32x4, z3);
        #pragma unroll
        for (int e = 0; e < 4; ++e){
          sh = __builtin_fmaf(zf0[e], whr[e0 + e], sh);      sc = __builtin_fmaf(zf0[e], wcr[e0 + e], sc);
          sh = __builtin_fmaf(zf1[e], whr[e0 + 4 + e], sh);  sc = __builtin_fmaf(zf1[e], wcr[e0 + 4 + e], sc);
          sh = __builtin_fmaf(zf2[e], whr[e0 + 8 + e], sh);  sc = __builtin_fmaf(zf2[e], wcr[e0 + 8 + e], sc);
          sh = __builtin_fmaf(zf3[e], whr[e0 + 12 + e], sh); sc = __builtin_fmaf(zf3[e], wcr[e0 + 12 + e], sc);
        }
      }
      c[r] = tanh_(sc);
      st16x<SAME>(hbuf0 + (size_t)b * Hn + jcol, (unsigned)f2bf(tanh_(sh)));
    }
    if (nt == 0 && tid < 3 * 64)
      st32x<SAME>(obuf + (tid >> 6) * Bt + mt * 64 + (tid & 63), bov);
    bars += 16; group_sync(cnt, bars);

    // -------- decoder: 1024 autoregressive steps --------
    for (int t = 0; t < Tt; ++t){
      const unsigned short* hs = (t & 1) ? hbuf1 : hbuf0;
      unsigned short*       hd = (t & 1) ? hbuf0 : hbuf1;
      float*       oacc  = obuf + (t % 3) * Bt;
      const float* oread = obuf + ((t + 2) % 3) * Bt;
      float*       orst  = obuf + ((t + 1) % 3) * Bt;

      if (nt == 0){
        if (t > 0 && tid < 64){
          float w = ld32w<SAME>(oread + mt * 64 + tid);
          stP32(out + (size_t)(mt * 64 + tid) * Tt + (t - 1), w);
        }
        if (tid < 64) st32x<SAME>(orst + mt * 64 + tid, bov);
      }

      u32x4 xvv = ldA<SAME, 0>(oread + brow0);
      const unsigned short* ap = hs + (size_t)arow0 * Hn + kq;
      LOADC1(0,   0); LOADC1(1, 128); LOADC1(2, 256); LOADC1(3, 384);

      f32x4 acc[4] = {fz, fz, fz, fz};
      const short* bbase = bpanel + (wn * 64 + l15) * BSD + kq;
      WAITC1(0, "12"); COMPC1(0,   0, BSD);
      WAITC1(1,  "8"); COMPC1(1, 128, BSD);
      WAITC1(2,  "4"); COMPC1(2, 256, BSD);
      WAITC1(3,  "0"); COMPC1(3, 384, BSD);
      asm volatile("s_waitcnt vmcnt(0)" : "+v"(xvv));
      f32x4 xf = __builtin_bit_cast(f32x4, xvv);

      #pragma unroll
      for (int r = 0; r < 4; ++r){
        float x = (t == 0) ? 0.f : xf[r];
        float gi = acc[0][r] + biasr[0] + x * wihr[0];
        float gf = acc[1][r] + biasr[1] + x * wihr[1];
        float gg = acc[2][r] + biasr[2] + x * wihr[2];
        float go = acc[3][r] + biasr[3] + x * wihr[3];
        float cn = sigm(gf) * c[r] + sigm(gi) * tanh_(gg);
        c[r] = cn;
        float hn = sigm(go) * tanh_(cn);
        hst[(wm * 16 + l4 * 4 + r) * HST + wn * 16 + l15] = f2bf(hn);
        float pv = hn * woutr;
        pv += __shfl_xor(pv, 1);
        pv += __shfl_xor(pv, 2);
        pv += __shfl_xor(pv, 4);
        pv += __shfl_xor(pv, 8);
        if (l15 == 0) atomAddF<SAME>(&oacc[brow0 + r], pv);
      }
      __syncthreads();
      if (tid < 256){
        int row = tid >> 2, sub = tid & 3;
        u32x4 hv = *(const u32x4*)(hst + row * HST + sub * 8);
        st128x<SAME>(hd + (size_t)(mt * 64 + row) * Hn + nt * 32 + sub * 8, hv);
      }
      bars += 16; group_sync(cnt, bars);
    }
    // drain last output column (t=1023 accumulated into buf 0)
    if (nt == 0 && tid < 64){
      float w = ld32w<SAME>(obuf + 0 * Bt + mt * 64 + tid);
      stP32(out + (size_t)(mt * 64 + tid) * Tt + (Tt - 1), w);
    }
  };

  if (same_xcd) body(BoolC<true>{});
  else          body(BoolC<false>{});
}

extern "C" void kernel_launch(void* const* d_in, const int* in_sizes, int n_in,
                              void* d_out, int out_size, void* d_ws, size_t ws_size,
                              hipStream_t stream){
  (void)in_sizes; (void)n_in; (void)out_size; (void)ws_size;
  const float* src   = (const float*)d_in[0];
  const float* eps   = (const float*)d_in[1];
  const float* Wih_e = (const float*)d_in[3];
  const float* Whh_e = (const float*)d_in[4];
  const float* b_e   = (const float*)d_in[5];
  const float* Wmu   = (const float*)d_in[6];
  const float* bmu   = (const float*)d_in[7];
  const float* Wlv   = (const float*)d_in[8];
  const float* blv   = (const float*)d_in[9];
  const float* Wzh   = (const float*)d_in[10];
  const float* bzh   = (const float*)d_in[11];
  const float* Wzc   = (const float*)d_in[12];
  const float* bzc   = (const float*)d_in[13];
  const float* Wih_d = (const float*)d_in[14];
  const float* Whh_d = (const float*)d_in[15];
  const float* b_d   = (const float*)d_in[16];
  const float* Wout  = (const float*)d_in[17];
  const float* bout  = (const float*)d_in[18];

  char* ws = (char*)d_ws;
  unsigned*       cnt   = (unsigned*)ws;                             // 16 groups x 128B
  unsigned*       xcdb  = (unsigned*)(ws + 2048);                    // 16 groups x 64B
  unsigned short* h0    = (unsigned short*)(ws + 4096);              // 1 MB
  unsigned short* h1    = (unsigned short*)(ws + 4096 + 1048576);    // 1 MB
  float*          zbuf  = (float*)(ws + 4096 + 2 * 1048576);         // 256 KB
  float*          obuf  = (float*)(ws + 4096 + 2 * 1048576 + 262144);// 12 KB

  hipFuncSetAttribute((const void*)vae_fused,
                      hipFuncAttributeMaxDynamicSharedMemorySize, LDS_BYTES);
  (void)hipMemsetAsync(ws, 0, 4096, stream);
  hipLaunchKernelGGL(vae_fused, dim3(NWG), dim3(NTHR), LDS_BYTES, stream,
                     src, eps, Wih_e, Whh_e, b_e, Wmu, bmu, Wlv, blv,
                     Wzh, bzh, Wzc, bzc, Wih_d, Whh_d, b_d, Wout, bout,
                     (float*)d_out, cnt, xcdb, h0, h1, zbuf, obuf);
}